// Round 5
// baseline (2276.191 us; speedup 1.0000x reference)
//
#include <hip/hip_runtime.h>
#include <type_traits>
#include <utility>

// ---------------------------------------------------------------------------
// HyenaFilter: y[b,c,l] = sum_{j<=l} k[c,j] x[b,c,l-j] + bias[c] x[b,c,l]
// Direct causal conv as bf16 MFMA 32x32x16, one 1024-thread block per channel.
// R8: ping-pong software pipeline. R7's loop compiled to {15 DS loads ->
// wait -> 16 MFMA} (VGPR=56: no cross-iter prefetch); 16 in-phase waves pay
// DS (2368cy) + MFMA (2048cy) SERIALLY per global iter = 159k cyc/round,
// matching measured 181k. Fix: two named register sets, body =
// {LOAD(b); MFMA(a); LOAD(a); MFMA(b)} -> loads issued one iter ahead,
// counted lgkmcnt, DS overlaps MFMA. Wave table rebuilt with EVEN spans
// (ping-pong needs even trip counts): per-SIMD sums exactly 144,
// spans 16..48. Reg cost 2x44 + 64 acc ~ 160 unified << 512 budget.
// Filter kernel unchanged from R7 (2 dispatches).
// ---------------------------------------------------------------------------

typedef __attribute__((ext_vector_type(4))) short  short4v;
typedef __attribute__((ext_vector_type(8))) short  short8v;
typedef __attribute__((ext_vector_type(8))) __bf16 bf16x8;
typedef __attribute__((ext_vector_type(16))) float f32x16;

// --- MFMA builtin operand-type hedge (short8 vs v8bf16) --------------------
template <typename V, typename = void> struct MfmaTakes : std::false_type {};
template <typename V>
struct MfmaTakes<V, std::void_t<decltype(__builtin_amdgcn_mfma_f32_32x32x16_bf16(
    std::declval<V>(), std::declval<V>(), std::declval<f32x16>(), 0, 0, 0))>>
    : std::true_type {};

template <bool UseBf16> struct MfmaImpl;
template <> struct MfmaImpl<true> {
  template <typename V>
  static __device__ inline f32x16 run(V a, V b, f32x16 c) {
    return __builtin_amdgcn_mfma_f32_32x32x16_bf16(
        __builtin_bit_cast(bf16x8, a), __builtin_bit_cast(bf16x8, b), c, 0, 0, 0);
  }
};
template <> struct MfmaImpl<false> {
  template <typename V>
  static __device__ inline f32x16 run(V a, V b, f32x16 c) {
    return __builtin_amdgcn_mfma_f32_32x32x16_bf16(a, b, c, 0, 0, 0);
  }
};

__device__ inline f32x16 mfma_bf16(short8v a, short8v b, f32x16 c) {
  return MfmaImpl<MfmaTakes<bf16x8>::value>::run(a, b, c);
}

__device__ inline short8v pack8(short4v lo, short4v hi) {
  short8v v;
  v[0] = lo[0]; v[1] = lo[1]; v[2] = lo[2]; v[3] = lo[3];
  v[4] = hi[0]; v[5] = hi[1]; v[6] = hi[2]; v[7] = hi[3];
  return v;
}

// float -> bf16 bits, round-to-nearest-even (finite values only)
__device__ inline short f2bf(float f) {
  unsigned int u = __builtin_bit_cast(unsigned int, f);
  u += 0x7FFFu + ((u >> 16) & 1u);
  return (short)(u >> 16);
}
__device__ inline float bf2f(short s) {
  unsigned int u = ((unsigned int)(unsigned short)s) << 16;
  return __builtin_bit_cast(float, u);
}

// --- R8 wave->work mapping: EVEN spans, per-SIMD (wid&3) sums all 144 ------
// S0{16,48,38,42} S1{32,32,38,42} S2{40,40,32,32} S3{32,32,36,44}
// groups: G0:w0; G1:w1; G2:w4; G3:w5[0,32)+w10[32,64); G4:w2[0,40)+w6[40,80);
// G5:w14[0,32)+w3[32,64)+w7[64,96); G6:w8[0,38)+w9[38,76)+w11[76,112);
// G7:w15[0,44)+w12[44,86)+w13[86,128)
__device__ const unsigned char cGt[16]  = {0,1,4,5, 2,3,4,5, 6,6,3,6, 7,7,5,7};
__device__ const short         cN0[16]  = {0,0,0,32, 0,0,40,64, 0,38,32,76, 44,86,0,0};
__device__ const short         cN1[16]  = {16,32,40,64, 48,32,80,96, 38,76,64,112, 86,128,32,44};
__device__ const unsigned char cSLOT[16]= {255,255,255,0, 255,255,1,2, 255,3,4,5, 255,6,255,7};
__device__ const unsigned char cRA[16]  = {255,255,1,255, 255,4,255,255, 3,255,255,255, 6,255,0,255};
__device__ const unsigned char cRB[16]  = {255,255,255,255, 255,255,255,255, 5,255,255,255, 7,255,2,255};

// ---------------------------------------------------------------------------
// Kernel 1: fused filter. grid (512, 3): blockIdx.x = 16-l slice,
// blockIdx.y = 256-channel slice. Per-block MLP over its 16 rows (redundant
// across blockIdx.y, trivially cheap), then per-thread-channel Wout with
// LDS broadcasts. gk stored REVERSED: gkR[c][i] = bf16(k[c, 8191-i]).
// ---------------------------------------------------------------------------
__global__ __launch_bounds__(256) void hyena_filter(
    const float* __restrict__ z, const float* __restrict__ deltas,
    const float* __restrict__ W0, const float* __restrict__ b0,
    const float* __restrict__ W1, const float* __restrict__ b1,
    const float* __restrict__ W2, const float* __restrict__ b2,
    const float* __restrict__ freq, const float* __restrict__ Wout,
    short* __restrict__ gk) {
  __shared__ float zt[16][33];
  __shared__ __align__(16) float hA[16][64];
  __shared__ __align__(16) float hB[16][64];
  const int tid = threadIdx.x;
  const int l0 = blockIdx.x << 4;

  for (int i = tid; i < 16 * 33; i += 256) {
    int l = i / 33, e = i - l * 33;
    zt[l][e] = z[(l0 + l) * 33 + e];
  }
  __syncthreads();
  for (int i = tid; i < 1024; i += 256) {
    int l = i >> 6, o = i & 63;
    float s = b0[o];
    for (int e = 0; e < 33; ++e) s += zt[l][e] * W0[e * 64 + o];
    hA[l][o] = sinf(freq[o] * s);
  }
  __syncthreads();
  for (int i = tid; i < 1024; i += 256) {
    int l = i >> 6, o = i & 63;
    float s = b1[o];
#pragma unroll
    for (int e = 0; e < 64; e += 4) {
      const float4 h4 = *reinterpret_cast<const float4*>(&hA[l][e]);
      s += h4.x * W1[e * 64 + o] + h4.y * W1[(e + 1) * 64 + o] +
           h4.z * W1[(e + 2) * 64 + o] + h4.w * W1[(e + 3) * 64 + o];
    }
    hB[l][o] = sinf(freq[o] * s);
  }
  __syncthreads();
  for (int i = tid; i < 1024; i += 256) {
    int l = i >> 6, o = i & 63;
    float s = b2[o];
#pragma unroll
    for (int e = 0; e < 64; e += 4) {
      const float4 h4 = *reinterpret_cast<const float4*>(&hB[l][e]);
      s += h4.x * W2[e * 64 + o] + h4.y * W2[(e + 1) * 64 + o] +
           h4.z * W2[(e + 2) * 64 + o] + h4.w * W2[(e + 3) * 64 + o];
    }
    hA[l][o] = sinf(freq[o] * s);
  }
  __syncthreads();
  {
    const int c0 = (blockIdx.y << 8) + tid;  // one channel per thread
    float a[16];
#pragma unroll
    for (int j = 0; j < 16; ++j) a[j] = 0.f;
    for (int o = 0; o < 64; o += 4) {
      const float w0 = Wout[(o + 0) * 768 + c0];
      const float w1 = Wout[(o + 1) * 768 + c0];
      const float w2 = Wout[(o + 2) * 768 + c0];
      const float w3 = Wout[(o + 3) * 768 + c0];
#pragma unroll
      for (int j = 0; j < 16; ++j) {
        const float4 h4 = *reinterpret_cast<const float4*>(&hA[j][o]);
        a[j] += h4.x * w0 + h4.y * w1 + h4.z * w2 + h4.w * w3;
      }
    }
    const float del = fabsf(deltas[c0]);
#pragma unroll
    for (int j = 0; j < 16; ++j)
      a[j] *= expf(-(float)(l0 + j) * (1.f / 8191.f) * del);

    // reversed pack: gkR[c][i] = bf16(k[c,8191-i]); dword = {lo=even i, hi=odd i}
    unsigned int* gku = reinterpret_cast<unsigned int*>(gk + ((size_t)c0 << 13));
#pragma unroll
    for (int j = 0; j < 16; j += 2) {
      const unsigned int hi = (unsigned short)f2bf(a[j]);      // i = 8191-l0-j
      const unsigned int lo = (unsigned short)f2bf(a[j + 1]);  // i = 8190-l0-j
      gku[(8190 - l0 - j) >> 1] = lo | (hi << 16);
    }
  }
}

// ---------------------------------------------------------------------------
// Kernel 2: causal conv via MFMA. 1024 threads (16 waves) per channel.
//
// LDS: sKR[rho][u] = KR[u+rho], KR[t] = k[8207-t] = gkR[t-16] for t in
//      [16,8207] else 0.  sXB[b][1008+s] = bf16(x[b,c,s]); [0,1008) zero,
//      [9200,9224) pad. Row = 9224 shorts = 4612 dw == 4 (mod 32).
// Wave wid -> (G, [n0,n1)) via tables; position n: delta = 1024*(n>>4) +
// 16*(n&15); pointers decrement 16/pos, 784 at super-block end ((n&15)==15).
// Per position: A_k at ka-256k (k=0..3, 2x b64 each), B(w) at xa+256w
// (w=-3..3, b128), 16 MFMA k-major: acc[a] += A_k * B(a-k).
// PING-PONG: two register sets; loads for position n+1 issued before the
// MFMAs of position n -> DS pipe works under the matrix pipe.
// Reduction: storer waves (slot 0..7) dump acc pairs into sKR-as-f32 scratch
// (8 x 8KB), owner waves add their group's 0-2 slots and run the epilogue.
// ---------------------------------------------------------------------------

#define ACC_ST(ACC, P, OFF)                                           \
  do {                                                                \
    _Pragma("unroll") for (int q = 0; q < 4; ++q) {                   \
      float4 v;                                                       \
      v.x = ACC[4 * q + 0]; v.y = ACC[4 * q + 1];                     \
      v.z = ACC[4 * q + 2]; v.w = ACC[4 * q + 3];                     \
      *reinterpret_cast<float4*>((P) + (OFF) + (q << 8)) = v;         \
    }                                                                 \
  } while (0)

#define ACC_LD(ACC, P, OFF)                                           \
  do {                                                                \
    _Pragma("unroll") for (int q = 0; q < 4; ++q) {                   \
      const float4 v =                                                \
          *reinterpret_cast<const float4*>((P) + (OFF) + (q << 8));   \
      ACC[4 * q + 0] += v.x; ACC[4 * q + 1] += v.y;                   \
      ACC[4 * q + 2] += v.z; ACC[4 * q + 3] += v.w;                   \
    }                                                                 \
  } while (0)

#define EPI(ACC, A)                                                   \
  do {                                                                \
    const int lb = lwb + ((A) << 8);                                  \
    _Pragma("unroll") for (int q = 0; q < 4; ++q) {                   \
      const int l0q = lb + (q << 3);                                  \
      const short4v xs =                                              \
          *reinterpret_cast<const short4v*>(&sXB[bcol][1008 + l0q]);  \
      float4 o4;                                                      \
      o4.x = ACC[4 * q + 0] + bc * bf2f(xs[0]);                       \
      o4.y = ACC[4 * q + 1] + bc * bf2f(xs[1]);                       \
      o4.z = ACC[4 * q + 2] + bc * bf2f(xs[2]);                       \
      o4.w = ACC[4 * q + 3] + bc * bf2f(xs[3]);                       \
      *reinterpret_cast<float4*>(out + obase + l0q) = o4;             \
    }                                                                 \
  } while (0)

#define LOAD_SET(S)                                                   \
  A0##S = pack8(*reinterpret_cast<const short4v*>(ka),                \
                *reinterpret_cast<const short4v*>(ka + 4));           \
  A1##S = pack8(*reinterpret_cast<const short4v*>(ka - 256),          \
                *reinterpret_cast<const short4v*>(ka - 252));         \
  A2##S = pack8(*reinterpret_cast<const short4v*>(ka - 512),          \
                *reinterpret_cast<const short4v*>(ka - 508));         \
  A3##S = pack8(*reinterpret_cast<const short4v*>(ka - 768),          \
                *reinterpret_cast<const short4v*>(ka - 764));         \
  Bm3##S = *reinterpret_cast<const short8v*>(xa - 768);               \
  Bm2##S = *reinterpret_cast<const short8v*>(xa - 512);               \
  Bm1##S = *reinterpret_cast<const short8v*>(xa - 256);               \
  B0##S  = *reinterpret_cast<const short8v*>(xa);                     \
  B1##S  = *reinterpret_cast<const short8v*>(xa + 256);               \
  B2##S  = *reinterpret_cast<const short8v*>(xa + 512);               \
  B3##S  = *reinterpret_cast<const short8v*>(xa + 768);

#define MFMA_SET(S)                                                   \
  acc0 = mfma_bf16(A0##S, B0##S, acc0);                               \
  acc1 = mfma_bf16(A0##S, B1##S, acc1);                               \
  acc2 = mfma_bf16(A0##S, B2##S, acc2);                               \
  acc3 = mfma_bf16(A0##S, B3##S, acc3);                               \
  acc0 = mfma_bf16(A1##S, Bm1##S, acc0);                              \
  acc1 = mfma_bf16(A1##S, B0##S, acc1);                               \
  acc2 = mfma_bf16(A1##S, B1##S, acc2);                               \
  acc3 = mfma_bf16(A1##S, B2##S, acc3);                               \
  acc0 = mfma_bf16(A2##S, Bm2##S, acc0);                              \
  acc1 = mfma_bf16(A2##S, Bm1##S, acc1);                              \
  acc2 = mfma_bf16(A2##S, B0##S, acc2);                               \
  acc3 = mfma_bf16(A2##S, B1##S, acc3);                               \
  acc0 = mfma_bf16(A3##S, Bm3##S, acc0);                              \
  acc1 = mfma_bf16(A3##S, Bm2##S, acc1);                              \
  acc2 = mfma_bf16(A3##S, Bm1##S, acc2);                              \
  acc3 = mfma_bf16(A3##S, B0##S, acc3);

#define ADV(NN)                                                       \
  { const int dec_ = (((NN) & 15) == 15) ? 784 : 16; ka -= dec_; xa -= dec_; }

__global__ __launch_bounds__(1024, 4) void hyena_conv(
    const float* __restrict__ x, const float* __restrict__ bias,
    const short* __restrict__ gk, float* __restrict__ out) {
  constexpr int LPAD = 1008;
  constexpr int XROW = 9224;                       // 1008 + 8192 + 24 pad
  __shared__ __align__(16) short sKR[4][8240];     // 65920 B (+ f32 scratch)
  __shared__ __align__(16) short sXB[4][XROW];     // 73792 B ; total 139712 B
  const int c = blockIdx.x;
  const int tid = threadIdx.x;

  // stage x -> bf16 LDS rows, vectorized (2x float4 -> ds_write_b128)
  {
    const short8v z8 = {0, 0, 0, 0, 0, 0, 0, 0};
    for (int b = 0; b < 4; ++b) {
      const float* xr = x + ((b * 768 + c) << 13);
      if (tid < 126)
        *reinterpret_cast<short8v*>(&sXB[b][tid << 3]) = z8;
      if (tid >= 1021)
        *reinterpret_cast<short8v*>(&sXB[b][9200 + ((tid - 1021) << 3)]) = z8;
      const int s0 = tid << 3;
      const float4 f0 = *reinterpret_cast<const float4*>(xr + s0);
      const float4 f1 = *reinterpret_cast<const float4*>(xr + s0 + 4);
      short8v v;
      v[0] = f2bf(f0.x); v[1] = f2bf(f0.y); v[2] = f2bf(f0.z); v[3] = f2bf(f0.w);
      v[4] = f2bf(f1.x); v[5] = f2bf(f1.y); v[6] = f2bf(f1.z); v[7] = f2bf(f1.w);
      *reinterpret_cast<short8v*>(&sXB[b][LPAD + s0]) = v;
    }
  }
  // stage reversed filter, 4 shifted replicas (gk reversed: forward reads)
  {
    const short* gkr = gk + (c << 13);
    for (int r = 0; r < 4; ++r)
      for (int u = tid; u < 8240; u += 1024) {
        int t = u + r;
        short v = 0;
        if (t >= 16 && t <= 8207) v = gkr[t - 16];
        sKR[r][u] = v;
      }
  }
  __syncthreads();

  const int lane = tid & 63;
  const int wid  = tid >> 6;                       // 0..15
  const int i31  = lane & 31;
  const int half = lane >> 5;
  const int base = half << 3;
  const int tcol = i31 >> 2;
  const int bcol = i31 & 3;
  const float bc = bias[c];

  const int G    = cGt[wid];
  const int n0   = cN0[wid];
  const int n1   = cN1[wid];
  const int slot = cSLOT[wid];
  const int lbase = G << 10;

  const int af0 = 8207 - i31 + base;
  const int rho = af0 & 3;
  const int u00 = af0 & ~3;
  const int pb  = LPAD + lbase + (tcol << 5) + base;
  const int d0  = ((n0 >> 4) << 10) + ((n0 & 15) << 4);

  const short* ka = &sKR[rho][0] + (u00 + 16 - d0);
  const short* xa = &sXB[bcol][0] + (pb + 16 - d0);

  f32x16 acc0, acc1, acc2, acc3;
#pragma unroll
  for (int r = 0; r < 16; ++r) {
    acc0[r] = 0.f; acc1[r] = 0.f; acc2[r] = 0.f; acc3[r] = 0.f;
  }

  short8v A0a, A1a, A2a, A3a, Bm3a, Bm2a, Bm1a, B0a, B1a, B2a, B3a;
  short8v A0b, A1b, A2b, A3b, Bm3b, Bm2b, Bm1b, B0b, B1b, B2b, B3b;

  // prologue: load position n0, advance to n0+1
  LOAD_SET(a)
  ADV(n0)
  int n = n0;
#pragma unroll 1
  for (; n + 2 < n1; n += 2) {
    LOAD_SET(b)        // position n+1
    ADV(n + 1)
    MFMA_SET(a)        // position n
    LOAD_SET(a)        // position n+2
    ADV(n + 2)
    MFMA_SET(b)        // position n+1
  }
  // epilogue: n == n1-2 here (spans are even), set a = n1-2, ptr at n1-1
  LOAD_SET(b)
  MFMA_SET(a)
  MFMA_SET(b)

  // generalized K-split reduction: sKR reused as f32 scratch (8 x 2048 f32)
  __syncthreads();
  float* scr = reinterpret_cast<float*>(&sKR[0][0]);
  const int isOwner = (slot == 255);
  float* sp = scr + (isOwner ? 0 : slot * 2048) + (lane << 2);
  const int ra = cRA[wid], rb = cRB[wid];
  if (!isOwner) { ACC_ST(acc0, sp, 0); ACC_ST(acc1, sp, 1024); }
  __syncthreads();
  if (isOwner) {
    if (ra != 255) {
      float* lp = scr + ra * 2048 + (lane << 2);
      ACC_LD(acc0, lp, 0); ACC_LD(acc1, lp, 1024);
    }
    if (rb != 255) {
      float* lp = scr + rb * 2048 + (lane << 2);
      ACC_LD(acc0, lp, 0); ACC_LD(acc1, lp, 1024);
    }
  }
  __syncthreads();
  if (!isOwner) { ACC_ST(acc2, sp, 0); ACC_ST(acc3, sp, 1024); }
  __syncthreads();
  if (isOwner) {
    if (ra != 255) {
      float* lp = scr + ra * 2048 + (lane << 2);
      ACC_LD(acc2, lp, 0); ACC_LD(acc3, lp, 1024);
    }
    if (rb != 255) {
      float* lp = scr + rb * 2048 + (lane << 2);
      ACC_LD(acc2, lp, 0); ACC_LD(acc3, lp, 1024);
    }
    const int obase = ((bcol * 768 + c) << 13);
    const int lwb = lbase + (tcol << 5) + (half << 2);
    EPI(acc0, 0); EPI(acc1, 1); EPI(acc2, 2); EPI(acc3, 3);
  }
}

// ---------------------------------------------------------------------------
extern "C" void kernel_launch(void* const* d_in, const int* in_sizes, int n_in,
                              void* d_out, int out_size, void* d_ws, size_t ws_size,
                              hipStream_t stream) {
  const float* x      = (const float*)d_in[0];
  const float* bias   = (const float*)d_in[1];
  const float* z      = (const float*)d_in[2];
  const float* deltas = (const float*)d_in[3];
  const float* W0     = (const float*)d_in[4];
  const float* b0     = (const float*)d_in[5];
  const float* W1     = (const float*)d_in[6];
  const float* b1     = (const float*)d_in[7];
  const float* W2     = (const float*)d_in[8];
  const float* b2     = (const float*)d_in[9];
  const float* freq   = (const float*)d_in[10];
  const float* Wout   = (const float*)d_in[11];
  float* out = (float*)d_out;
  short* gk = (short*)d_ws;  // 768*8192*2 B = 12.6 MB reversed bf16 filter

  hipLaunchKernelGGL(hyena_filter, dim3(512, 3), dim3(256), 0, stream,
                     z, deltas, W0, b0, W1, b1, W2, b2, freq, Wout, gk);
  hipLaunchKernelGGL(hyena_conv, dim3(768), dim3(1024), 0, stream,
                     x, bias, gk, out);
}

// Round 6
// 416.423 us; speedup vs baseline: 5.4661x; 5.4661x over previous
//
#include <hip/hip_runtime.h>
#include <type_traits>
#include <utility>

// ---------------------------------------------------------------------------
// HyenaFilter: y[b,c,l] = sum_{j<=l} k[c,j] x[b,c,l-j] + bias[c] x[b,c,l]
// Direct causal conv as bf16 MFMA 32x32x16, one block per channel.
// R9: 8-wave ping-pong. R8's pipeline spilled: 1024 thr = 4 waves/SIMD =
// 128 VGPR cap < 170 needed (FETCH 55MB->2.9GB scratch traffic). Now 512
// threads = 2 waves/SIMD = 256 VGPR cap: full 2-set pipeline fits (~180).
// Complementary group pairing (w: G = w<4 ? w : 11-w) gives per-SIMD iter
// sums exactly 144 with NO K-split -> no scratch reduction, no tables, no
// post-loop barriers; solo tail waves stay pipelined (DS ~280cy hides under
// 512cy MFMA). DS port 8x148=1184 cyc/iter-equiv < 2048 matrix-pipe ->
// MFMA-bound. R7 convoy confirmed: MfmaUtil 47% == 2048/(2048+2368).
// Filter kernel unchanged from R7 (2 dispatches).
// ---------------------------------------------------------------------------

typedef __attribute__((ext_vector_type(4))) short  short4v;
typedef __attribute__((ext_vector_type(8))) short  short8v;
typedef __attribute__((ext_vector_type(8))) __bf16 bf16x8;
typedef __attribute__((ext_vector_type(16))) float f32x16;

// --- MFMA builtin operand-type hedge (short8 vs v8bf16) --------------------
template <typename V, typename = void> struct MfmaTakes : std::false_type {};
template <typename V>
struct MfmaTakes<V, std::void_t<decltype(__builtin_amdgcn_mfma_f32_32x32x16_bf16(
    std::declval<V>(), std::declval<V>(), std::declval<f32x16>(), 0, 0, 0))>>
    : std::true_type {};

template <bool UseBf16> struct MfmaImpl;
template <> struct MfmaImpl<true> {
  template <typename V>
  static __device__ inline f32x16 run(V a, V b, f32x16 c) {
    return __builtin_amdgcn_mfma_f32_32x32x16_bf16(
        __builtin_bit_cast(bf16x8, a), __builtin_bit_cast(bf16x8, b), c, 0, 0, 0);
  }
};
template <> struct MfmaImpl<false> {
  template <typename V>
  static __device__ inline f32x16 run(V a, V b, f32x16 c) {
    return __builtin_amdgcn_mfma_f32_32x32x16_bf16(a, b, c, 0, 0, 0);
  }
};

__device__ inline f32x16 mfma_bf16(short8v a, short8v b, f32x16 c) {
  return MfmaImpl<MfmaTakes<bf16x8>::value>::run(a, b, c);
}

__device__ inline short8v pack8(short4v lo, short4v hi) {
  short8v v;
  v[0] = lo[0]; v[1] = lo[1]; v[2] = lo[2]; v[3] = lo[3];
  v[4] = hi[0]; v[5] = hi[1]; v[6] = hi[2]; v[7] = hi[3];
  return v;
}

// float -> bf16 bits, round-to-nearest-even (finite values only)
__device__ inline short f2bf(float f) {
  unsigned int u = __builtin_bit_cast(unsigned int, f);
  u += 0x7FFFu + ((u >> 16) & 1u);
  return (short)(u >> 16);
}
__device__ inline float bf2f(short s) {
  unsigned int u = ((unsigned int)(unsigned short)s) << 16;
  return __builtin_bit_cast(float, u);
}

// ---------------------------------------------------------------------------
// Kernel 1: fused filter (unchanged from R7). grid (512, 3).
// gk stored REVERSED: gkR[c][i] = bf16(k[c, 8191-i]).
// ---------------------------------------------------------------------------
__global__ __launch_bounds__(256) void hyena_filter(
    const float* __restrict__ z, const float* __restrict__ deltas,
    const float* __restrict__ W0, const float* __restrict__ b0,
    const float* __restrict__ W1, const float* __restrict__ b1,
    const float* __restrict__ W2, const float* __restrict__ b2,
    const float* __restrict__ freq, const float* __restrict__ Wout,
    short* __restrict__ gk) {
  __shared__ float zt[16][33];
  __shared__ __align__(16) float hA[16][64];
  __shared__ __align__(16) float hB[16][64];
  const int tid = threadIdx.x;
  const int l0 = blockIdx.x << 4;

  for (int i = tid; i < 16 * 33; i += 256) {
    int l = i / 33, e = i - l * 33;
    zt[l][e] = z[(l0 + l) * 33 + e];
  }
  __syncthreads();
  for (int i = tid; i < 1024; i += 256) {
    int l = i >> 6, o = i & 63;
    float s = b0[o];
    for (int e = 0; e < 33; ++e) s += zt[l][e] * W0[e * 64 + o];
    hA[l][o] = sinf(freq[o] * s);
  }
  __syncthreads();
  for (int i = tid; i < 1024; i += 256) {
    int l = i >> 6, o = i & 63;
    float s = b1[o];
#pragma unroll
    for (int e = 0; e < 64; e += 4) {
      const float4 h4 = *reinterpret_cast<const float4*>(&hA[l][e]);
      s += h4.x * W1[e * 64 + o] + h4.y * W1[(e + 1) * 64 + o] +
           h4.z * W1[(e + 2) * 64 + o] + h4.w * W1[(e + 3) * 64 + o];
    }
    hB[l][o] = sinf(freq[o] * s);
  }
  __syncthreads();
  for (int i = tid; i < 1024; i += 256) {
    int l = i >> 6, o = i & 63;
    float s = b2[o];
#pragma unroll
    for (int e = 0; e < 64; e += 4) {
      const float4 h4 = *reinterpret_cast<const float4*>(&hB[l][e]);
      s += h4.x * W2[e * 64 + o] + h4.y * W2[(e + 1) * 64 + o] +
           h4.z * W2[(e + 2) * 64 + o] + h4.w * W2[(e + 3) * 64 + o];
    }
    hA[l][o] = sinf(freq[o] * s);
  }
  __syncthreads();
  {
    const int c0 = (blockIdx.y << 8) + tid;  // one channel per thread
    float a[16];
#pragma unroll
    for (int j = 0; j < 16; ++j) a[j] = 0.f;
    for (int o = 0; o < 64; o += 4) {
      const float w0 = Wout[(o + 0) * 768 + c0];
      const float w1 = Wout[(o + 1) * 768 + c0];
      const float w2 = Wout[(o + 2) * 768 + c0];
      const float w3 = Wout[(o + 3) * 768 + c0];
#pragma unroll
      for (int j = 0; j < 16; ++j) {
        const float4 h4 = *reinterpret_cast<const float4*>(&hA[j][o]);
        a[j] += h4.x * w0 + h4.y * w1 + h4.z * w2 + h4.w * w3;
      }
    }
    const float del = fabsf(deltas[c0]);
#pragma unroll
    for (int j = 0; j < 16; ++j)
      a[j] *= expf(-(float)(l0 + j) * (1.f / 8191.f) * del);

    unsigned int* gku = reinterpret_cast<unsigned int*>(gk + ((size_t)c0 << 13));
#pragma unroll
    for (int j = 0; j < 16; j += 2) {
      const unsigned int hi = (unsigned short)f2bf(a[j]);      // i = 8191-l0-j
      const unsigned int lo = (unsigned short)f2bf(a[j + 1]);  // i = 8190-l0-j
      gku[(8190 - l0 - j) >> 1] = lo | (hi << 16);
    }
  }
}

// ---------------------------------------------------------------------------
// Kernel 2: causal conv via MFMA. 512 threads (8 waves) per channel.
//
// LDS: sKR[rho][u] = KR[u+rho], KR[t] = k[8207-t] = gkR[t-16] for t in
//      [16,8207] else 0.  sXB[b][1008+s] = bf16(x[b,c,s]); [0,1008) zero,
//      [9200,9224) pad. Row = 9224 shorts = 4612 dw == 4 (mod 32).
// Wave wid (0..7) -> group G = wid<4 ? wid : 11-wid (SIMD = wid&3, pairs
// (w,w+4) sum to 144 iters exactly). n in [0, 16(G+1)): d = 1024*(n>>4) +
// 16*(n&15); pointers decrement 16/pos, 784 at super-block end.
// Per position: A_k at ka-256k (k=0..3, 2x b64), B(w) at xa+256w (b128),
// 16 MFMA k-major: acc[a] += A_k * B(a-k). Tap set {1024q+256k+16r} =
// exact partition of [0,1024(G+1)) (verified R7 invariant, n0=0 case).
// PING-PONG: two named register sets, loads of position n+1 issued before
// MFMAs of position n. 64 acc + 88 operand + addr ~ 180 VGPR < 256 cap
// (2 waves/SIMD). No K-split -> no scratch, no reduction barriers; each
// wave owns its group and writes its own epilogue.
// ---------------------------------------------------------------------------

#define EPI(ACC, A)                                                   \
  do {                                                                \
    const int lb = lwb + ((A) << 8);                                  \
    _Pragma("unroll") for (int q = 0; q < 4; ++q) {                   \
      const int l0q = lb + (q << 3);                                  \
      const short4v xs =                                              \
          *reinterpret_cast<const short4v*>(&sXB[bcol][1008 + l0q]);  \
      float4 o4;                                                      \
      o4.x = ACC[4 * q + 0] + bc * bf2f(xs[0]);                       \
      o4.y = ACC[4 * q + 1] + bc * bf2f(xs[1]);                       \
      o4.z = ACC[4 * q + 2] + bc * bf2f(xs[2]);                       \
      o4.w = ACC[4 * q + 3] + bc * bf2f(xs[3]);                       \
      *reinterpret_cast<float4*>(out + obase + l0q) = o4;             \
    }                                                                 \
  } while (0)

#define LOAD_SET(S)                                                   \
  A0##S = pack8(*reinterpret_cast<const short4v*>(ka),                \
                *reinterpret_cast<const short4v*>(ka + 4));           \
  A1##S = pack8(*reinterpret_cast<const short4v*>(ka - 256),          \
                *reinterpret_cast<const short4v*>(ka - 252));         \
  A2##S = pack8(*reinterpret_cast<const short4v*>(ka - 512),          \
                *reinterpret_cast<const short4v*>(ka - 508));         \
  A3##S = pack8(*reinterpret_cast<const short4v*>(ka - 768),          \
                *reinterpret_cast<const short4v*>(ka - 764));         \
  Bm3##S = *reinterpret_cast<const short8v*>(xa - 768);               \
  Bm2##S = *reinterpret_cast<const short8v*>(xa - 512);               \
  Bm1##S = *reinterpret_cast<const short8v*>(xa - 256);               \
  B0##S  = *reinterpret_cast<const short8v*>(xa);                     \
  B1##S  = *reinterpret_cast<const short8v*>(xa + 256);               \
  B2##S  = *reinterpret_cast<const short8v*>(xa + 512);               \
  B3##S  = *reinterpret_cast<const short8v*>(xa + 768);

#define MFMA_SET(S)                                                   \
  acc0 = mfma_bf16(A0##S, B0##S, acc0);                               \
  acc1 = mfma_bf16(A0##S, B1##S, acc1);                               \
  acc2 = mfma_bf16(A0##S, B2##S, acc2);                               \
  acc3 = mfma_bf16(A0##S, B3##S, acc3);                               \
  acc0 = mfma_bf16(A1##S, Bm1##S, acc0);                              \
  acc1 = mfma_bf16(A1##S, B0##S, acc1);                               \
  acc2 = mfma_bf16(A1##S, B1##S, acc2);                               \
  acc3 = mfma_bf16(A1##S, B2##S, acc3);                               \
  acc0 = mfma_bf16(A2##S, Bm2##S, acc0);                              \
  acc1 = mfma_bf16(A2##S, Bm1##S, acc1);                              \
  acc2 = mfma_bf16(A2##S, B0##S, acc2);                               \
  acc3 = mfma_bf16(A2##S, B1##S, acc3);                               \
  acc0 = mfma_bf16(A3##S, Bm3##S, acc0);                              \
  acc1 = mfma_bf16(A3##S, Bm2##S, acc1);                              \
  acc2 = mfma_bf16(A3##S, Bm1##S, acc2);                              \
  acc3 = mfma_bf16(A3##S, B0##S, acc3);

#define ADV(NN)                                                       \
  { const int dec_ = (((NN) & 15) == 15) ? 784 : 16; ka -= dec_; xa -= dec_; }

__global__ __launch_bounds__(512, 2) void hyena_conv(
    const float* __restrict__ x, const float* __restrict__ bias,
    const short* __restrict__ gk, float* __restrict__ out) {
  constexpr int LPAD = 1008;
  constexpr int XROW = 9224;                       // 1008 + 8192 + 24 pad
  __shared__ __align__(16) short sKR[4][8240];     // 65920 B
  __shared__ __align__(16) short sXB[4][XROW];     // 73792 B ; total 139712 B
  const int c = blockIdx.x;
  const int tid = threadIdx.x;

  // stage x -> bf16 LDS rows (coalesced float4 -> ds_write_b64)
  {
    const short8v z8 = {0, 0, 0, 0, 0, 0, 0, 0};
    for (int b = 0; b < 4; ++b) {
      const float* xr = x + ((b * 768 + c) << 13);
      if (tid < 126)
        *reinterpret_cast<short8v*>(&sXB[b][tid << 3]) = z8;
      if (tid >= 509)
        *reinterpret_cast<short8v*>(&sXB[b][9200 + ((tid - 509) << 3)]) = z8;
#pragma unroll
      for (int j = 0; j < 4; ++j) {
        const int s0 = (j << 11) + (tid << 2);
        const float4 f = *reinterpret_cast<const float4*>(xr + s0);
        short4v v;
        v[0] = f2bf(f.x); v[1] = f2bf(f.y); v[2] = f2bf(f.z); v[3] = f2bf(f.w);
        *reinterpret_cast<short4v*>(&sXB[b][LPAD + s0]) = v;
      }
    }
  }
  // stage reversed filter, 4 shifted replicas (gk reversed: forward reads)
  {
    const short* gkr = gk + (c << 13);
    for (int r = 0; r < 4; ++r)
      for (int u = tid; u < 8240; u += 512) {
        int t = u + r;
        short v = 0;
        if (t >= 16 && t <= 8207) v = gkr[t - 16];
        sKR[r][u] = v;
      }
  }
  __syncthreads();

  const int lane = tid & 63;
  const int wid  = tid >> 6;                       // 0..7
  const int i31  = lane & 31;
  const int half = lane >> 5;
  const int base = half << 3;
  const int tcol = i31 >> 2;
  const int bcol = i31 & 3;
  const float bc = bias[c];

  const int G  = (wid < 4) ? wid : (11 - wid);     // SIMD pair sums = 144
  const int n1 = (G + 1) << 4;
  const int lbase = G << 10;

  const int af0 = 8207 - i31 + base;
  const int rho = af0 & 3;
  const int u00 = af0 & ~3;
  const int pb  = LPAD + lbase + (tcol << 5) + base;

  const short* ka = &sKR[rho][0] + (u00 + 16);
  const short* xa = &sXB[bcol][0] + (pb + 16);

  f32x16 acc0, acc1, acc2, acc3;
#pragma unroll
  for (int r = 0; r < 16; ++r) {
    acc0[r] = 0.f; acc1[r] = 0.f; acc2[r] = 0.f; acc3[r] = 0.f;
  }

  short8v A0a, A1a, A2a, A3a, Bm3a, Bm2a, Bm1a, B0a, B1a, B2a, B3a;
  short8v A0b, A1b, A2b, A3b, Bm3b, Bm2b, Bm1b, B0b, B1b, B2b, B3b;

  // prologue: load position 0, advance
  LOAD_SET(a)
  ADV(0)
  int n = 0;
#pragma unroll 1
  for (; n + 2 < n1; n += 2) {
    LOAD_SET(b)        // position n+1
    ADV(n + 1)
    MFMA_SET(a)        // position n
    LOAD_SET(a)        // position n+2
    ADV(n + 2)
    MFMA_SET(b)        // position n+1
  }
  // epilogue: n == n1-2 (spans even); pointer at position n1-1
  LOAD_SET(b)
  MFMA_SET(a)
  MFMA_SET(b)

  // epilogue: y = acc + bias*x  (x read back from LDS as bf16); no
  // cross-wave reduction -- each wave owns its group outright.
  const int obase = ((bcol * 768 + c) << 13);
  const int lwb = lbase + (tcol << 5) + (half << 2);
  EPI(acc0, 0); EPI(acc1, 1); EPI(acc2, 2); EPI(acc3, 3);
}

// ---------------------------------------------------------------------------
extern "C" void kernel_launch(void* const* d_in, const int* in_sizes, int n_in,
                              void* d_out, int out_size, void* d_ws, size_t ws_size,
                              hipStream_t stream) {
  const float* x      = (const float*)d_in[0];
  const float* bias   = (const float*)d_in[1];
  const float* z      = (const float*)d_in[2];
  const float* deltas = (const float*)d_in[3];
  const float* W0     = (const float*)d_in[4];
  const float* b0     = (const float*)d_in[5];
  const float* W1     = (const float*)d_in[6];
  const float* b1     = (const float*)d_in[7];
  const float* W2     = (const float*)d_in[8];
  const float* b2     = (const float*)d_in[9];
  const float* freq   = (const float*)d_in[10];
  const float* Wout   = (const float*)d_in[11];
  float* out = (float*)d_out;
  short* gk = (short*)d_ws;  // 768*8192*2 B = 12.6 MB reversed bf16 filter

  hipLaunchKernelGGL(hyena_filter, dim3(512, 3), dim3(256), 0, stream,
                     z, deltas, W0, b0, W1, b1, W2, b2, freq, Wout, gk);
  hipLaunchKernelGGL(hyena_conv, dim3(768), dim3(512), 0, stream,
                     x, bias, gk, out);
}